// Round 7
// baseline (150.224 us; speedup 1.0000x reference)
//
#include <hip/hip_runtime.h>
#include <math.h>

#define G     1000
#define B     32
#define NC    2048
#define NT    2048
#define BN    (B * NT)
#define LOG2E 1.4426950408889634f
#define LN2PI 1.8378770664093453f   // ln(2*pi)

#if __has_builtin(__builtin_amdgcn_exp2f)
#define EXP2F(x) __builtin_amdgcn_exp2f(x)
#else
#define EXP2F(x) exp2f(x)
#endif

// ---------------------------------------------------------------------------
// Kernel A v3 (frozen): grid (16 g-tiles x B), block 512 = 64g x 8n.
// ---------------------------------------------------------------------------
__global__ __launch_bounds__(512) void k_smooth(
    const float* __restrict__ xc, const float* __restrict__ yc,
    const float* __restrict__ ls_x, float* __restrict__ h,
    float* __restrict__ loss_slot) {
  __shared__ float sxy[NC * 2];           // {s*x_n, y_n} interleaved, 16KB
  __shared__ float pm[512], ps[512];
  if (blockIdx.x == 0 && blockIdx.y == 0 && threadIdx.x == 0) *loss_slot = 0.f;

  int tid = threadIdx.x;
  int b = blockIdx.y, tile = blockIdx.x;
  float ls = ls_x[0];
  float s  = sqrtf(0.5f * LOG2E) / ls;    // w = exp2(-(s*t - s*x)^2)

  const float* xb = xc + b * NC;
  const float* yb = yc + b * NC;
  for (int n = tid; n < NC; n += 512) {
    sxy[2 * n]     = s * xb[n];
    sxy[2 * n + 1] = yb[n];
  }
  __syncthreads();

  int gl = tid & 63, q = tid >> 6;        // 64 g-slots x 8 n-slices
  int g  = tile * 64 + gl;
  float tgp = s * (-2.2f + (4.4f / 999.f) * (float)g);

  float s0 = 0.f, s1 = 0.f;
  const float4* p = ((const float4*)sxy) + q * (NC / 16);
  #pragma unroll 4
  for (int i = 0; i < NC / 16; ++i) {
    float4 v = p[i];
    float d0 = tgp - v.x; float w0 = EXP2F(-(d0 * d0));
    float d1 = tgp - v.z; float w1 = EXP2F(-(d1 * d1));
    s0 += w0; s1 = fmaf(w0, v.y, s1);
    s0 += w1; s1 = fmaf(w1, v.w, s1);
  }
  pm[tid] = s0; ps[tid] = s1;
  __syncthreads();

  if (q == 0 && g < G) {
    float d0 = s0, d1 = s1;
    #pragma unroll
    for (int k = 1; k < 8; ++k) { d0 += pm[tid + 64 * k]; d1 += ps[tid + 64 * k]; }
    h[(b * 2 + 0) * G + g] = d0;
    h[(b * 2 + 1) * G + g] = d1 / (d0 + 1e-8f);
  }
}

// ---------------------------------------------------------------------------
// Kernel B v5 (frozen, launched 9x this round for attribution):
// TILE=48, grid (21 x B) = 672 blocks, ~40KB LDS.
// ---------------------------------------------------------------------------
#define TILE  48
#define NTILE 21   // 21*48 = 1008 >= 1000
#define CSTR  68

template <int CIN, int COUT, int WSTR, int NPASS>
__device__ __forceinline__ void conv_layer5(
    const float* __restrict__ in, float* __restrict__ out,
    const float* __restrict__ wt, const float* __restrict__ bias, int tid) {
  #pragma unroll
  for (int pass = 0; pass < NPASS; ++pass) {
    int idx = tid + pass * 256;           // < COUT*16 by construction
    int oc  = idx % COUT;
    int i0  = (idx / COUT) * 4;           // reads [i0, i0+8), writes [i0+2, i0+6)
    float acc[4];
    float bb = bias[oc];
    #pragma unroll
    for (int p = 0; p < 4; ++p) acc[p] = bb;
    for (int ic = 0; ic < CIN; ++ic) {
      const float* ip = in + ic * CSTR + i0;
      float4 va = *(const float4*)ip;
      float4 vb = *(const float4*)(ip + 4);
      float v[8] = {va.x, va.y, va.z, va.w, vb.x, vb.y, vb.z, vb.w};
      const float* wp = wt + oc * WSTR + ic * 5;
      float w[5];
      #pragma unroll
      for (int k = 0; k < 5; ++k) w[k] = wp[k];
      #pragma unroll
      for (int p = 0; p < 4; ++p)
        #pragma unroll
        for (int k = 0; k < 5; ++k)
          acc[p] = fmaf(v[p + k], w[k], acc[p]);
    }
    float* op = out + oc * CSTR + i0 + 2;
    *(float2*)op       = make_float2(fmaxf(acc[0], 0.f), fmaxf(acc[1], 0.f));
    *(float2*)(op + 2) = make_float2(fmaxf(acc[2], 0.f), fmaxf(acc[3], 0.f));
  }
}

__global__ __launch_bounds__(256, 4) void k_conv(
    const float* __restrict__ h,
    const float* __restrict__ W1, const float* __restrict__ Bs1,
    const float* __restrict__ W2, const float* __restrict__ Bs2,
    const float* __restrict__ W3, const float* __restrict__ Bs3,
    const float* __restrict__ W4, const float* __restrict__ Bs4,
    float* __restrict__ yg) {
  __shared__ __align__(16) float bufA[32 * CSTR], bufB[32 * CSTR];
  __shared__ float wt1[176], wt2[2592], wt3[2576], wt4[162];
  __shared__ float sB1[16], sB2[32], sB3[16], sB4[2];

  int tid  = threadIdx.x;
  int tile = blockIdx.x, b = blockIdx.y;
  int ts   = tile * TILE;

  // coalesced weight staging into padded natural-layout strides
  for (int i = tid; i < 160;  i += 256) wt1[(i / 10)  * 11  + i % 10]  = W1[i];
  for (int i = tid; i < 2560; i += 256) wt2[(i / 80)  * 81  + i % 80]  = W2[i];
  for (int i = tid; i < 2560; i += 256) wt3[(i / 160) * 161 + i % 160] = W3[i];
  for (int i = tid; i < 160;  i += 256) wt4[(i / 80)  * 81  + i % 80]  = W4[i];
  if (tid < 16)       sB1[tid]      = Bs1[tid];
  else if (tid < 48)  sB2[tid - 16] = Bs2[tid - 16];
  else if (tid < 64)  sB3[tid - 48] = Bs3[tid - 48];
  else if (tid < 66)  sB4[tid - 64] = Bs4[tid - 64];

  // stage input: col i in [0,68) <-> global g = ts + i - 10
  for (int i = tid; i < 2 * CSTR; i += 256) {
    int c = i >= CSTR, col = i - c * CSTR;
    int g = ts + col - 10;
    bufA[c * CSTR + col] = (g >= 0 && g < G) ? h[(b * 2 + c) * G + g] : 0.f;
  }
  __syncthreads();

  conv_layer5<2, 16, 11, 1>(bufA, bufB, wt1, sB1, tid);
  __syncthreads();
  conv_layer5<16, 32, 81, 2>(bufB, bufA, wt2, sB2, tid);
  __syncthreads();
  conv_layer5<32, 16, 161, 1>(bufA, bufB, wt3, sB3, tid);
  __syncthreads();

  // Layer 4: 96 threads, thread -> (oc, one output); softplus on ch1
  if (tid < 96) {
    int oc = tid >= 48;
    int j  = tid - oc * 48;               // 0..47
    int i  = 10 + j;
    float sacc = sB4[oc];
    #pragma unroll
    for (int ic = 0; ic < 16; ++ic) {
      const float* ip = bufB + ic * CSTR + i - 2;
      #pragma unroll
      for (int k = 0; k < 5; ++k)
        sacc = fmaf(ip[k], wt4[oc * 81 + ic * 5 + k], sacc);
    }
    int gp = ts + j;
    if (gp < G) {
      if (oc == 0) {
        yg[(b * 2 + 0) * G + gp] = sacc;
      } else {
        float sp_ = fmaxf(sacc, 0.f) + log1pf(__expf(-fabsf(sacc)));
        yg[(b * 2 + 1) * G + gp] = sp_;
      }
    }
  }
}

// ---------------------------------------------------------------------------
// Kernel C v4 (frozen): Gaussian recurrence — no exp in the loop.
// ---------------------------------------------------------------------------
__global__ __launch_bounds__(512) void k_pred(
    const float* __restrict__ xt, const float* __restrict__ yt,
    const float* __restrict__ ls_rho, const float* __restrict__ yg,
    float* __restrict__ out) {
  __shared__ float2 sp[G];                // {y0_g, y1_g}, 8KB
  __shared__ float pm[512], ps[512];
  __shared__ float red[8];

  int tid = threadIdx.x;
  int b = blockIdx.y, tile = blockIdx.x;
  float ls = ls_rho[0];
  float s  = sqrtf(0.5f * LOG2E) / ls;
  float dl = s * (4.4f / 999.f);          // delta

  const float* y0 = yg + (b * 2 + 0) * G;
  const float* y1 = yg + (b * 2 + 1) * G;
  for (int g = tid; g < G; g += 512) sp[g] = make_float2(y0[g], y1[g]);
  __syncthreads();

  int tl = tid & 127, qi = tid >> 7;      // 128 t x 4 slices (250 g each)
  int t  = tile * 128 + tl;
  float u  = s * xt[b * NT + t];
  float a  = u + 2.2f * s - dl * (float)(qi * 250);  // u - v_{g0}
  float W  = EXP2F(64.f - a * a);
  float q  = EXP2F(dl * (a + a) - dl * dl);
  float r  = EXP2F(-2.f * dl * dl);

  float mu = 0.f, sg = 0.f;
  const float2* p = sp + qi * 250;
  #pragma unroll 2
  for (int i = 0; i < 250; ++i) {
    float2 v = p[i];
    mu = fmaf(W, v.x, mu);
    sg = fmaf(W, v.y, sg);
    W *= q;
    q *= r;
  }
  pm[tid] = mu; ps[tid] = sg;
  __syncthreads();

  float lp = 0.f;
  if (qi == 0) {
    #pragma unroll
    for (int k = 1; k < 4; ++k) { mu += pm[tid + 128 * k]; sg += ps[tid + 128 * k]; }
    mu *= 0x1p-64f;                        // undo 2^64 scaling
    sg *= 0x1p-64f;
    out[b * NT + t]      = mu;
    out[BN + b * NT + t] = sg;
    float z = (yt[b * NT + t] - mu) / sg;
    lp = -0.5f * z * z - __logf(sg) - 0.5f * LN2PI;
  }
  #pragma unroll
  for (int m = 32; m; m >>= 1) lp += __shfl_xor(lp, m);
  if ((tid & 63) == 0) red[tid >> 6] = lp;
  __syncthreads();
  if (tid == 0) {
    float tot = 0.f;
    #pragma unroll
    for (int i = 0; i < 8; ++i) tot += red[i];
    atomicAdd(out + 2 * BN, -tot * (1.f / (float)NT));
  }
}

extern "C" void kernel_launch(void* const* d_in, const int* in_sizes, int n_in,
                              void* d_out, int out_size, void* d_ws, size_t ws_size,
                              hipStream_t stream) {
  const float* xc  = (const float*)d_in[0];
  const float* yc  = (const float*)d_in[1];
  const float* xt  = (const float*)d_in[2];
  const float* yt  = (const float*)d_in[3];
  const float* lsx = (const float*)d_in[4];
  const float* lsr = (const float*)d_in[5];
  const float* W1  = (const float*)d_in[6];  const float* b1 = (const float*)d_in[7];
  const float* W2  = (const float*)d_in[8];  const float* b2 = (const float*)d_in[9];
  const float* W3  = (const float*)d_in[10]; const float* b3 = (const float*)d_in[11];
  const float* W4  = (const float*)d_in[12]; const float* b4 = (const float*)d_in[13];

  float* out = (float*)d_out;
  float* h   = (float*)d_ws;        // B*2*G
  float* yg  = h + B * 2 * G;       // B*2*G

  k_smooth<<<dim3(16, B), 512, 0, stream>>>(xc, yc, lsx, h, out + 2 * BN);
  // ATTRIBUTION: launch conv 9x (idempotent). (D - 50.7)/8 = conv + gap.
  for (int rep = 0; rep < 9; ++rep)
    k_conv<<<dim3(NTILE, B), 256, 0, stream>>>(h, W1, b1, W2, b2, W3, b3, W4, b4, yg);
  k_pred<<<dim3(16, B), 512, 0, stream>>>(xt, yt, lsr, yg, out);
}

// Round 8
// 44.523 us; speedup vs baseline: 3.3741x; 3.3741x over previous
//
#include <hip/hip_runtime.h>
#include <math.h>

#define G     1000
#define B     32
#define NC    2048
#define NT    2048
#define BN    (B * NT)
#define LOG2E 1.4426950408889634f
#define LN2PI 1.8378770664093453f   // ln(2*pi)

#if __has_builtin(__builtin_amdgcn_exp2f)
#define EXP2F(x) __builtin_amdgcn_exp2f(x)
#else
#define EXP2F(x) exp2f(x)
#endif

// ---------------------------------------------------------------------------
// Kernel A v4: block 512 = 8 n-slices (1/wave) x 64 lanes; each lane owns 2 g
// (lane, lane+64). Per f4 LDS read (2 pairs) -> 4 evals: DS-instr count per CU
// halved vs v3. Grid (8, B) = 256 blocks = 1 per CU.
// ---------------------------------------------------------------------------
__global__ __launch_bounds__(512) void k_smooth(
    const float* __restrict__ xc, const float* __restrict__ yc,
    const float* __restrict__ ls_x, float* __restrict__ h,
    float* __restrict__ loss_slot) {
  __shared__ float sxy[NC * 2];           // {s*x_n, y_n} interleaved, 16KB
  __shared__ float pA0[512], pA1[512], pB0[512], pB1[512];
  if (blockIdx.x == 0 && blockIdx.y == 0 && threadIdx.x == 0) *loss_slot = 0.f;

  int tid = threadIdx.x;
  int b = blockIdx.y, tile = blockIdx.x;  // tile 0..7, covers g in [128*tile, 128*tile+128)
  float ls = ls_x[0];
  float s  = sqrtf(0.5f * LOG2E) / ls;    // w = exp2(-(s*t - s*x)^2)

  const float* xb = xc + b * NC;
  const float* yb = yc + b * NC;
  for (int n = tid; n < NC; n += 512) {
    sxy[2 * n]     = s * xb[n];
    sxy[2 * n + 1] = yb[n];
  }
  __syncthreads();

  int lane = tid & 63, wv = tid >> 6;     // wv = n-slice 0..7
  int ga = tile * 128 + lane;             // lane's two g: ga, ga+64
  float step = s * (4.4f / 999.f);
  float tga = s * -2.2f + step * (float)ga;
  float tgb = tga + step * 64.f;

  float a0 = 0.f, a1 = 0.f, b0 = 0.f, b1 = 0.f;
  const float4* p = ((const float4*)sxy) + wv * (NC / 16);  // 128 f4 per slice
  #pragma unroll 4
  for (int i = 0; i < NC / 16; ++i) {
    float4 v = p[i];
    float d, w;
    d = tga - v.x; w = EXP2F(-(d * d)); a0 += w; a1 = fmaf(w, v.y, a1);
    d = tgb - v.x; w = EXP2F(-(d * d)); b0 += w; b1 = fmaf(w, v.y, b1);
    d = tga - v.z; w = EXP2F(-(d * d)); a0 += w; a1 = fmaf(w, v.w, a1);
    d = tgb - v.z; w = EXP2F(-(d * d)); b0 += w; b1 = fmaf(w, v.w, b1);
  }
  pA0[tid] = a0; pA1[tid] = a1; pB0[tid] = b0; pB1[tid] = b1;
  __syncthreads();

  if (tid < 128) {
    int which = tid >> 6, l = tid & 63;
    int g = tile * 128 + which * 64 + l;
    if (g < G) {
      const float* q0 = which ? pB0 : pA0;
      const float* q1 = which ? pB1 : pA1;
      float d0 = 0.f, d1 = 0.f;
      #pragma unroll
      for (int k = 0; k < 8; ++k) { d0 += q0[l + 64 * k]; d1 += q1[l + 64 * k]; }
      h[(b * 2 + 0) * G + g] = d0;
      h[(b * 2 + 1) * G + g] = d1 / (d0 + 1e-8f);
    }
  }
}

// ---------------------------------------------------------------------------
// Kernel B v5 (frozen): TILE=48, grid (21 x B) = 672 blocks, ~40KB LDS.
// Measured r7: conv + launch gap = 12.4us.
// ---------------------------------------------------------------------------
#define TILE  48
#define NTILE 21   // 21*48 = 1008 >= 1000
#define CSTR  68

template <int CIN, int COUT, int WSTR, int NPASS>
__device__ __forceinline__ void conv_layer5(
    const float* __restrict__ in, float* __restrict__ out,
    const float* __restrict__ wt, const float* __restrict__ bias, int tid) {
  #pragma unroll
  for (int pass = 0; pass < NPASS; ++pass) {
    int idx = tid + pass * 256;
    int oc  = idx % COUT;
    int i0  = (idx / COUT) * 4;
    float acc[4];
    float bb = bias[oc];
    #pragma unroll
    for (int p = 0; p < 4; ++p) acc[p] = bb;
    for (int ic = 0; ic < CIN; ++ic) {
      const float* ip = in + ic * CSTR + i0;
      float4 va = *(const float4*)ip;
      float4 vb = *(const float4*)(ip + 4);
      float v[8] = {va.x, va.y, va.z, va.w, vb.x, vb.y, vb.z, vb.w};
      const float* wp = wt + oc * WSTR + ic * 5;
      float w[5];
      #pragma unroll
      for (int k = 0; k < 5; ++k) w[k] = wp[k];
      #pragma unroll
      for (int p = 0; p < 4; ++p)
        #pragma unroll
        for (int k = 0; k < 5; ++k)
          acc[p] = fmaf(v[p + k], w[k], acc[p]);
    }
    float* op = out + oc * CSTR + i0 + 2;
    *(float2*)op       = make_float2(fmaxf(acc[0], 0.f), fmaxf(acc[1], 0.f));
    *(float2*)(op + 2) = make_float2(fmaxf(acc[2], 0.f), fmaxf(acc[3], 0.f));
  }
}

__global__ __launch_bounds__(256, 4) void k_conv(
    const float* __restrict__ h,
    const float* __restrict__ W1, const float* __restrict__ Bs1,
    const float* __restrict__ W2, const float* __restrict__ Bs2,
    const float* __restrict__ W3, const float* __restrict__ Bs3,
    const float* __restrict__ W4, const float* __restrict__ Bs4,
    float* __restrict__ yg) {
  __shared__ __align__(16) float bufA[32 * CSTR], bufB[32 * CSTR];
  __shared__ float wt1[176], wt2[2592], wt3[2576], wt4[162];
  __shared__ float sB1[16], sB2[32], sB3[16], sB4[2];

  int tid  = threadIdx.x;
  int tile = blockIdx.x, b = blockIdx.y;
  int ts   = tile * TILE;

  for (int i = tid; i < 160;  i += 256) wt1[(i / 10)  * 11  + i % 10]  = W1[i];
  for (int i = tid; i < 2560; i += 256) wt2[(i / 80)  * 81  + i % 80]  = W2[i];
  for (int i = tid; i < 2560; i += 256) wt3[(i / 160) * 161 + i % 160] = W3[i];
  for (int i = tid; i < 160;  i += 256) wt4[(i / 80)  * 81  + i % 80]  = W4[i];
  if (tid < 16)       sB1[tid]      = Bs1[tid];
  else if (tid < 48)  sB2[tid - 16] = Bs2[tid - 16];
  else if (tid < 64)  sB3[tid - 48] = Bs3[tid - 48];
  else if (tid < 66)  sB4[tid - 64] = Bs4[tid - 64];

  for (int i = tid; i < 2 * CSTR; i += 256) {
    int c = i >= CSTR, col = i - c * CSTR;
    int g = ts + col - 10;
    bufA[c * CSTR + col] = (g >= 0 && g < G) ? h[(b * 2 + c) * G + g] : 0.f;
  }
  __syncthreads();

  conv_layer5<2, 16, 11, 1>(bufA, bufB, wt1, sB1, tid);
  __syncthreads();
  conv_layer5<16, 32, 81, 2>(bufB, bufA, wt2, sB2, tid);
  __syncthreads();
  conv_layer5<32, 16, 161, 1>(bufA, bufB, wt3, sB3, tid);
  __syncthreads();

  if (tid < 96) {
    int oc = tid >= 48;
    int j  = tid - oc * 48;
    int i  = 10 + j;
    float sacc = sB4[oc];
    #pragma unroll
    for (int ic = 0; ic < 16; ++ic) {
      const float* ip = bufB + ic * CSTR + i - 2;
      #pragma unroll
      for (int k = 0; k < 5; ++k)
        sacc = fmaf(ip[k], wt4[oc * 81 + ic * 5 + k], sacc);
    }
    int gp = ts + j;
    if (gp < G) {
      if (oc == 0) {
        yg[(b * 2 + 0) * G + gp] = sacc;
      } else {
        float sp_ = fmaxf(sacc, 0.f) + log1pf(__expf(-fabsf(sacc)));
        yg[(b * 2 + 1) * G + gp] = sp_;
      }
    }
  }
}

// ---------------------------------------------------------------------------
// Kernel C v5: Gaussian recurrence, 2 t per thread. Block 512 = 8 g-slices
// (1/wave, 125 g each) x 64 lanes; lane owns t = tile*128+lane and +64 with
// independent recurrence state. Grid (16, B) = 512 blocks.
// out: [0,BN) mu | [BN,2BN) sigma | [2BN] loss
// ---------------------------------------------------------------------------
__global__ __launch_bounds__(512) void k_pred(
    const float* __restrict__ xt, const float* __restrict__ yt,
    const float* __restrict__ ls_rho, const float* __restrict__ yg,
    float* __restrict__ out) {
  __shared__ float2 sp[G];                // {y0_g, y1_g}, 8KB
  __shared__ float pA0[512], pA1[512], pB0[512], pB1[512];
  __shared__ float red[8];

  int tid = threadIdx.x;
  int b = blockIdx.y, tile = blockIdx.x;  // tile 0..15
  float ls = ls_rho[0];
  float s  = sqrtf(0.5f * LOG2E) / ls;
  float dl = s * (4.4f / 999.f);

  const float* y0 = yg + (b * 2 + 0) * G;
  const float* y1 = yg + (b * 2 + 1) * G;
  for (int g = tid; g < G; g += 512) sp[g] = make_float2(y0[g], y1[g]);
  __syncthreads();

  int lane = tid & 63, wv = tid >> 6;     // wv = g-slice 0..7 (125 g each)
  int ta = tile * 128 + lane;             // lane's two t: ta, ta+64
  float ua = s * xt[b * NT + ta];
  float ub = s * xt[b * NT + ta + 64];
  float base = 2.2f * s - dl * (float)(wv * 125);
  float aa = ua + base, ab = ub + base;   // a^2 <= ~130 -> W in [2^-66, 2^64]
  float Wa = EXP2F(64.f - aa * aa), qa = EXP2F(dl * (aa + aa) - dl * dl);
  float Wb = EXP2F(64.f - ab * ab), qb = EXP2F(dl * (ab + ab) - dl * dl);
  float r  = EXP2F(-2.f * dl * dl);

  float muA = 0.f, sgA = 0.f, muB = 0.f, sgB = 0.f;
  const float2* p = sp + wv * 125;
  #pragma unroll 5
  for (int i = 0; i < 125; ++i) {
    float2 v = p[i];
    muA = fmaf(Wa, v.x, muA); sgA = fmaf(Wa, v.y, sgA); Wa *= qa; qa *= r;
    muB = fmaf(Wb, v.x, muB); sgB = fmaf(Wb, v.y, sgB); Wb *= qb; qb *= r;
  }
  pA0[tid] = muA; pA1[tid] = sgA; pB0[tid] = muB; pB1[tid] = sgB;
  __syncthreads();

  float lp = 0.f;
  if (tid < 128) {
    int which = tid >> 6, l = tid & 63;
    int t = tile * 128 + which * 64 + l;
    const float* q0 = which ? pB0 : pA0;
    const float* q1 = which ? pB1 : pA1;
    float mu = 0.f, sg = 0.f;
    #pragma unroll
    for (int k = 0; k < 8; ++k) { mu += q0[l + 64 * k]; sg += q1[l + 64 * k]; }
    mu *= 0x1p-64f;                        // undo 2^64 scaling
    sg *= 0x1p-64f;
    out[b * NT + t]      = mu;
    out[BN + b * NT + t] = sg;
    float z = (yt[b * NT + t] - mu) / sg;
    lp = -0.5f * z * z - __logf(sg) - 0.5f * LN2PI;
  }
  #pragma unroll
  for (int m = 32; m; m >>= 1) lp += __shfl_xor(lp, m);
  if ((tid & 63) == 0) red[tid >> 6] = lp;
  __syncthreads();
  if (tid == 0) {
    float tot = 0.f;
    #pragma unroll
    for (int i = 0; i < 8; ++i) tot += red[i];
    atomicAdd(out + 2 * BN, -tot * (1.f / (float)NT));
  }
}

extern "C" void kernel_launch(void* const* d_in, const int* in_sizes, int n_in,
                              void* d_out, int out_size, void* d_ws, size_t ws_size,
                              hipStream_t stream) {
  const float* xc  = (const float*)d_in[0];
  const float* yc  = (const float*)d_in[1];
  const float* xt  = (const float*)d_in[2];
  const float* yt  = (const float*)d_in[3];
  const float* lsx = (const float*)d_in[4];
  const float* lsr = (const float*)d_in[5];
  const float* W1  = (const float*)d_in[6];  const float* b1 = (const float*)d_in[7];
  const float* W2  = (const float*)d_in[8];  const float* b2 = (const float*)d_in[9];
  const float* W3  = (const float*)d_in[10]; const float* b3 = (const float*)d_in[11];
  const float* W4  = (const float*)d_in[12]; const float* b4 = (const float*)d_in[13];

  float* out = (float*)d_out;
  float* h   = (float*)d_ws;        // B*2*G
  float* yg  = h + B * 2 * G;       // B*2*G

  k_smooth<<<dim3(8, B), 512, 0, stream>>>(xc, yc, lsx, h, out + 2 * BN);
  k_conv<<<dim3(NTILE, B), 256, 0, stream>>>(h, W1, b1, W2, b2, W3, b3, W4, b4, yg);
  k_pred<<<dim3(16, B), 512, 0, stream>>>(xt, yt, lsr, yg, out);
}